// Round 6
// baseline (96.052 us; speedup 1.0000x reference)
//
#include <hip/hip_runtime.h>
#include <hip/hip_bf16.h>

// DCellLinear: y[s] = x[s] @ W[s]^T + b[s], s = 0..4095 (f32 in/out, bf16 MFMA)
// 539 MB irreducible @ 6.29 TB/s copy ceiling => 85.7 us floor.
// R5 (R3 + nontemporal) = 92.3 us: nt-bypass of L2 allocation was +17%.
// R6 = R5 made PERSISTENT: 512 blocks x 256 thr, 8 subsystems each (2 blocks/CU,
// zero tail). Per iter the nt-loads for s+1 are issued BEFORE compute/store of s,
// so the read queue never drains across the compute+slab+store phases (T14).
// Panels: x 16K @0 + W 32K @16384, rows 256 B, XOR-swizzle byte^=(row&7)<<4.
// Epilogue: acc -> per-wave f32 slab [64][36] (reuses panel LDS) -> linear nt-store.

typedef __attribute__((ext_vector_type(8))) short bf16x8;
typedef __attribute__((ext_vector_type(4))) float f32x4;

constexpr int NSUB = 4096, BATCH = 64, DIN = 128, DOUT = 128;
constexpr int SPB  = 8;
constexpr int NBLK = NSUB / SPB;     // 512
constexpr int XOFF = 0, WOFF = 16384;

__device__ __forceinline__ unsigned pk2(float lo, float hi) {
    __hip_bfloat162 h = __float22bfloat162_rn(make_float2(lo, hi));  // v_cvt_pk_bf16_f32
    unsigned u; __builtin_memcpy(&u, &h, 4);
    return u;
}
__device__ __forceinline__ f32x4 ntld(const float* p) {
    return __builtin_nontemporal_load(reinterpret_cast<const f32x4*>(p));
}
__device__ __forceinline__ void ntst(float* p, f32x4 v) {
    __builtin_nontemporal_store(v, reinterpret_cast<f32x4*>(p));
}

__global__ __launch_bounds__(256, 2)
void dcell(const float* __restrict__ X, const float* __restrict__ W,
           const float* __restrict__ Bv, float* __restrict__ Y)
{
    __shared__ __align__(16) char lds[49152];
    const int tid  = threadIdx.x;
    const int lane = tid & 63;
    const int wv   = tid >> 6;
    const int qw   = lane >> 4;
    const int lr   = lane & 15;
    const int n0   = wv * 32;
    const int sb   = blockIdx.x * SPB;

    f32x4 xr[8], wr[16];                       // staged next-subsystem (96 VGPR)
    auto loadS = [&](int s) {
        const float* xp = X + (size_t)s * (BATCH * DIN);
        const float* wp = W + (size_t)s * (DOUT * DIN);
        #pragma unroll
        for (int i = 0; i < 8; ++i)  xr[i] = ntld(xp + 4 * (tid + 256 * i));
        #pragma unroll
        for (int i = 0; i < 16; ++i) wr[i] = ntld(wp + 4 * (tid + 256 * i));
    };
    auto writePanels = [&]() {                 // cvt f32->bf16, swizzled rows
        #pragma unroll
        for (int i = 0; i < 8; ++i) {
            const int c = tid + 256 * i, row = c >> 5, colb = (c & 31) * 8;
            uint2 p; p.x = pk2(xr[i][0], xr[i][1]); p.y = pk2(xr[i][2], xr[i][3]);
            *reinterpret_cast<uint2*>(lds + XOFF + row * 256 + (colb ^ ((row & 7) << 4))) = p;
        }
        #pragma unroll
        for (int i = 0; i < 16; ++i) {
            const int c = tid + 256 * i, row = c >> 5, colb = (c & 31) * 8;
            uint2 p; p.x = pk2(wr[i][0], wr[i][1]); p.y = pk2(wr[i][2], wr[i][3]);
            *reinterpret_cast<uint2*>(lds + WOFF + row * 256 + (colb ^ ((row & 7) << 4))) = p;
        }
    };

    // prologue: stage s0, panels up, one barrier
    loadS(sb);
    writePanels();
    __syncthreads();

    for (int t = 0; t < SPB; ++t) {
        const int s = sb + t;
        if (t + 1 < SPB) loadS(s + 1);         // issue-early: in flight across s

        // bias -> acc (C/D: col=lane&15, row=qw*4+reg [m89]; bias col-only)
        f32x4 acc[4][2];
        {
            const float* bs = Bv + (size_t)s * DOUT + n0;
            #pragma unroll
            for (int nt = 0; nt < 2; ++nt) {
                const float bb = bs[nt * 16 + lr];
                #pragma unroll
                for (int mt = 0; mt < 4; ++mt) {
                    acc[mt][nt][0] = bb; acc[mt][nt][1] = bb;
                    acc[mt][nt][2] = bb; acc[mt][nt][3] = bb;
                }
            }
        }
        // 4 MFMA k-steps from panels
        #pragma unroll
        for (int k0 = 0; k0 < DIN; k0 += 32) {
            bf16x8 bfr[2];
            #pragma unroll
            for (int nt = 0; nt < 2; ++nt) {
                const int row = n0 + nt * 16 + lr;
                const int colb = ((k0 + qw * 8) * 2) ^ ((row & 7) << 4);
                bfr[nt] = *reinterpret_cast<const bf16x8*>(lds + WOFF + row * 256 + colb);
            }
            #pragma unroll
            for (int mt = 0; mt < 4; ++mt) {
                const int row = mt * 16 + lr;
                const int colb = ((k0 + qw * 8) * 2) ^ ((row & 7) << 4);
                const bf16x8 afr = *reinterpret_cast<const bf16x8*>(lds + XOFF + row * 256 + colb);
                #pragma unroll
                for (int nt = 0; nt < 2; ++nt)
                    acc[mt][nt] = __builtin_amdgcn_mfma_f32_16x16x32_bf16(
                        afr, bfr[nt], acc[mt][nt], 0, 0, 0);
            }
        }
        __syncthreads();                        // panels dead

        // acc -> per-wave slab [64][36] f32 (reuses panel LDS)
        float* slab = reinterpret_cast<float*>(lds) + wv * 2304;
        #pragma unroll
        for (int mt = 0; mt < 4; ++mt)
            #pragma unroll
            for (int j = 0; j < 4; ++j) {
                const int row = mt * 16 + qw * 4 + j;
                #pragma unroll
                for (int nt = 0; nt < 2; ++nt)
                    slab[row * 36 + nt * 16 + lr] = acc[mt][nt][j];
            }
        __syncthreads();                        // slab complete

        // linear nt stores: 32 KB contiguous
        float* od = Y + (size_t)s * (BATCH * DOUT);
        const float* lf = reinterpret_cast<const float*>(lds);
        #pragma unroll
        for (int i = 0; i < 8; ++i) {
            const int c = tid + 256 * i;
            const int row = c >> 5, col4 = (c & 31) * 4;
            const f32x4 v = *reinterpret_cast<const f32x4*>(
                lf + (col4 >> 5) * 2304 + row * 36 + (col4 & 31));
            ntst(od + 4 * c, v);
        }

        if (t + 1 < SPB) {
            __syncthreads();                    // slab reads done
            writePanels();                      // s+1 (waitcnt drains its loads here)
            __syncthreads();                    // panels ready
        }
    }
}

extern "C" void kernel_launch(void* const* d_in, const int* in_sizes, int n_in,
                              void* d_out, int out_size, void* d_ws, size_t ws_size,
                              hipStream_t stream) {
    const float* X  = (const float*)d_in[0];
    const float* W  = (const float*)d_in[1];
    const float* Bv = (const float*)d_in[2];
    float*       Y  = (float*)d_out;
    dcell<<<NBLK, 256, 0, stream>>>(X, W, Bv, Y);
}

// Round 7
// 92.497 us; speedup vs baseline: 1.0384x; 1.0384x over previous
//
#include <hip/hip_runtime.h>
#include <hip/hip_bf16.h>

// DCellLinear: y[s] = x[s] @ W[s]^T + b[s], s = 0..4095 (f32 in/out, bf16 MFMA)
// 539 MB irreducible @ 6.29 TB/s copy ceiling => 85.7 us floor.
// R5 (one-shot + nontemporal) = 92.3 us (5.84 TB/s). R6 persistent = 96.1 (occupancy
// drop to 2 blocks/CU). R7 raises TLP instead: split W panel into two K-halves so
// static LDS = max(16K x + 16K Whalf, 36K slab) = 36 KB -> 4 blocks/CU (16 waves),
// VGPR <= 128 via __launch_bounds__(256,4). Half-1 W loads issued before half-0
// MFMA (in flight under compute). All R5-verified paths otherwise unchanged.

typedef __attribute__((ext_vector_type(8))) short bf16x8;
typedef __attribute__((ext_vector_type(4))) float f32x4;

constexpr int NSUB = 4096, BATCH = 64, DIN = 128, DOUT = 128;
constexpr int XOFF = 0;        // x panel [64 rows][256 B] bf16 (full K) = 16 KB
constexpr int WOFF = 16384;    // W half-panel [128 rows][128 B] bf16    = 16 KB
constexpr int LDSB = 36864;    // slab phase ([64][36] f32 x 4 waves) overlays panels

__device__ __forceinline__ unsigned pk2(float lo, float hi) {
    __hip_bfloat162 h = __float22bfloat162_rn(make_float2(lo, hi));  // v_cvt_pk_bf16_f32
    unsigned u; __builtin_memcpy(&u, &h, 4);
    return u;
}
__device__ __forceinline__ f32x4 ntld(const float* p) {
    return __builtin_nontemporal_load(reinterpret_cast<const f32x4*>(p));
}
__device__ __forceinline__ void ntst(float* p, f32x4 v) {
    __builtin_nontemporal_store(v, reinterpret_cast<f32x4*>(p));
}

__global__ __launch_bounds__(256, 4)
void dcell(const float* __restrict__ X, const float* __restrict__ W,
           const float* __restrict__ Bv, float* __restrict__ Y)
{
    __shared__ __align__(16) char lds[LDSB];
    const int s    = blockIdx.x;
    const int tid  = threadIdx.x;
    const int lane = tid & 63;
    const int wv   = tid >> 6;
    const int qw   = lane >> 4;
    const int lr   = lane & 15;
    const int n0   = wv * 32;          // wave's 32 output cols

    const float* xsrc = X + (size_t)s * (BATCH * DIN);
    const float* wsrc = W + (size_t)s * (DOUT * DIN);

    // ---- issue x (32 KB) + W K-half-0 (16 KB) nt loads ----
    f32x4 xr[8], wr[8];
    #pragma unroll
    for (int i = 0; i < 8; ++i) xr[i] = ntld(xsrc + 4 * (tid + 256 * i));
    #pragma unroll
    for (int i = 0; i < 8; ++i) {
        const int c = tid + 256 * i, row = c >> 4;       // 16 f32x4-chunks per row-half
        wr[i] = ntld(wsrc + (size_t)row * DIN + (c & 15) * 4);
    }

    // ---- cvt + write panels (byte ^= (row&7)<<4 swizzle) ----
    #pragma unroll
    for (int i = 0; i < 8; ++i) {
        const int c = tid + 256 * i, row = c >> 5, colb = (c & 31) * 8;
        uint2 p; p.x = pk2(xr[i][0], xr[i][1]); p.y = pk2(xr[i][2], xr[i][3]);
        *reinterpret_cast<uint2*>(lds + XOFF + row * 256 + (colb ^ ((row & 7) << 4))) = p;
    }
    #pragma unroll
    for (int i = 0; i < 8; ++i) {
        const int c = tid + 256 * i, row = c >> 4, colb = (c & 15) * 8;
        uint2 p; p.x = pk2(wr[i][0], wr[i][1]); p.y = pk2(wr[i][2], wr[i][3]);
        *reinterpret_cast<uint2*>(lds + WOFF + row * 128 + (colb ^ ((row & 7) << 4))) = p;
    }
    __syncthreads();

    // ---- issue W K-half-1 loads (ride under half-0 MFMA) ----
    #pragma unroll
    for (int i = 0; i < 8; ++i) {
        const int c = tid + 256 * i, row = c >> 4;
        wr[i] = ntld(wsrc + (size_t)row * DIN + 64 + (c & 15) * 4);
    }

    // ---- bias -> acc (C/D: col=lane&15, row=qw*4+reg [m89]) ----
    f32x4 acc[4][2];
    {
        const float* bs = Bv + (size_t)s * DOUT + n0;
        #pragma unroll
        for (int nt = 0; nt < 2; ++nt) {
            const float bb = bs[nt * 16 + lr];
            #pragma unroll
            for (int mt = 0; mt < 4; ++mt) {
                acc[mt][nt][0] = bb; acc[mt][nt][1] = bb;
                acc[mt][nt][2] = bb; acc[mt][nt][3] = bb;
            }
        }
    }

    // ---- MFMA K-half 0 (kglobal 0..63) ----
    #pragma unroll
    for (int kk = 0; kk < 2; ++kk) {
        const int kl = kk * 32;                          // local == global this half
        bf16x8 bfr[2];
        #pragma unroll
        for (int nt = 0; nt < 2; ++nt) {
            const int row = n0 + nt * 16 + lr;
            const int colb = ((kl + qw * 8) * 2) ^ ((row & 7) << 4);
            bfr[nt] = *reinterpret_cast<const bf16x8*>(lds + WOFF + row * 128 + colb);
        }
        #pragma unroll
        for (int mt = 0; mt < 4; ++mt) {
            const int row = mt * 16 + lr;
            const int colb = ((kl + qw * 8) * 2) ^ ((row & 7) << 4);
            const bf16x8 afr = *reinterpret_cast<const bf16x8*>(lds + XOFF + row * 256 + colb);
            #pragma unroll
            for (int nt = 0; nt < 2; ++nt)
                acc[mt][nt] = __builtin_amdgcn_mfma_f32_16x16x32_bf16(
                    afr, bfr[nt], acc[mt][nt], 0, 0, 0);
        }
    }
    __syncthreads();                                     // W half-0 panel dead

    // ---- write W K-half-1 panel ----
    #pragma unroll
    for (int i = 0; i < 8; ++i) {
        const int c = tid + 256 * i, row = c >> 4, colb = (c & 15) * 8;
        uint2 p; p.x = pk2(wr[i][0], wr[i][1]); p.y = pk2(wr[i][2], wr[i][3]);
        *reinterpret_cast<uint2*>(lds + WOFF + row * 128 + (colb ^ ((row & 7) << 4))) = p;
    }
    __syncthreads();

    // ---- MFMA K-half 1 (kglobal 64..127, panel-local 0..63) ----
    #pragma unroll
    for (int kk = 0; kk < 2; ++kk) {
        const int kl = kk * 32;
        bf16x8 bfr[2];
        #pragma unroll
        for (int nt = 0; nt < 2; ++nt) {
            const int row = n0 + nt * 16 + lr;
            const int colb = ((kl + qw * 8) * 2) ^ ((row & 7) << 4);
            bfr[nt] = *reinterpret_cast<const bf16x8*>(lds + WOFF + row * 128 + colb);
        }
        #pragma unroll
        for (int mt = 0; mt < 4; ++mt) {
            const int row = mt * 16 + lr;
            const int colb = ((64 + kl + qw * 8) * 2) ^ ((row & 7) << 4);
            const bf16x8 afr = *reinterpret_cast<const bf16x8*>(lds + XOFF + row * 256 + colb);
            #pragma unroll
            for (int nt = 0; nt < 2; ++nt)
                acc[mt][nt] = __builtin_amdgcn_mfma_f32_16x16x32_bf16(
                    afr, bfr[nt], acc[mt][nt], 0, 0, 0);
        }
    }
    __syncthreads();                                     // panels dead; slab overlays

    // ---- acc -> per-wave f32 slab [64][36] (pad kills write conflicts) ----
    float* slab = reinterpret_cast<float*>(lds) + wv * 2304;
    #pragma unroll
    for (int mt = 0; mt < 4; ++mt)
        #pragma unroll
        for (int j = 0; j < 4; ++j) {
            const int row = mt * 16 + qw * 4 + j;
            #pragma unroll
            for (int nt = 0; nt < 2; ++nt)
                slab[row * 36 + nt * 16 + lr] = acc[mt][nt][j];
        }
    __syncthreads();

    // ---- fully-linear nt stores: 32 KB contiguous per block ----
    float* od = Y + (size_t)s * (BATCH * DOUT);
    const float* lf = reinterpret_cast<const float*>(lds);
    #pragma unroll
    for (int i = 0; i < 8; ++i) {
        const int c = tid + 256 * i;
        const int row = c >> 5, col4 = (c & 31) * 4;
        const f32x4 v = *reinterpret_cast<const f32x4*>(
            lf + (col4 >> 5) * 2304 + row * 36 + (col4 & 31));
        ntst(od + 4 * c, v);
    }
}

extern "C" void kernel_launch(void* const* d_in, const int* in_sizes, int n_in,
                              void* d_out, int out_size, void* d_ws, size_t ws_size,
                              hipStream_t stream) {
    const float* X  = (const float*)d_in[0];
    const float* W  = (const float*)d_in[1];
    const float* Bv = (const float*)d_in[2];
    float*       Y  = (float*)d_out;
    dcell<<<NSUB, 256, 0, stream>>>(X, W, Bv, Y);
}